// Round 15
// baseline (156.829 us; speedup 1.0000x reference)
//
#include <hip/hip_runtime.h>
#include <stdint.h>

#define L_SEQ 2048
#define HID   2048
#define NHEAD 32
#define NKV   8
#define HD    64
#define KVDIM 512
#define QSCALE 0.18033688f         /* log2(e)/8 folded into Q at projection */

typedef __attribute__((ext_vector_type(8))) short s16x8;
typedef __attribute__((ext_vector_type(4))) short s16x4;
typedef __attribute__((ext_vector_type(4))) float f32x4;

// native RNE f32->bf16 (v_cvt_pk_bf16_f32 on gfx950)
__device__ __forceinline__ short f2bf(float f) {
  __bf16 b = (__bf16)f;
  short s;
  __builtin_memcpy(&s, &b, 2);
  return s;
}

// async global->LDS, 16B/lane. Linear LDS dest + inverse-swizzled global
// source + swizzled read (rule #21).
__device__ __forceinline__ void gload16(const void* g, void* l) {
  __builtin_amdgcn_global_load_lds(
      (const __attribute__((address_space(1))) void*)g,
      (__attribute__((address_space(3))) void*)l, 16, 0, 0);
}

// ---------------- fused weight-convert (Wq/Wk/Wv) + RMSNorm ----------------
// blocks 0..2047: rmsnorm rows; 2048..8191: f32->bf16 for Wq/Wk/Wv.
// Wo conversion rides inside the attn dispatch (overlaps compute-bound attn).
__global__ __launch_bounds__(256) void pre_kernel(
    const float* __restrict__ x, const float* __restrict__ w,
    const float* __restrict__ wq, const float* __restrict__ wk,
    const float* __restrict__ wv,
    short* __restrict__ h,
    short* __restrict__ owq, short* __restrict__ owk,
    short* __restrict__ owv) {
  const int tid = threadIdx.x;
  if (blockIdx.x >= 2048) {
    int64_t e = ((int64_t)(blockIdx.x - 2048) * 256 + tid) * 4;
    const float* src; short* dst; int64_t o;
    if (e < 4194304)      { src = wq; dst = owq; o = e; }
    else if (e < 5242880) { src = wk; dst = owk; o = e - 4194304; }
    else                  { src = wv; dst = owv; o = e - 5242880; }
    f32x4 v = *(const f32x4*)(src + o);
    s16x4 b;
    b[0] = f2bf(v[0]); b[1] = f2bf(v[1]); b[2] = f2bf(v[2]); b[3] = f2bf(v[3]);
    *(s16x4*)(dst + o) = b;
    return;
  }
  const int row = blockIdx.x;
  const float* xr = x + (int64_t)row * HID + tid * 8;
  f32x4 a = *(const f32x4*)(xr);
  f32x4 b = *(const f32x4*)(xr + 4);
  float ss = a[0]*a[0]+a[1]*a[1]+a[2]*a[2]+a[3]*a[3]
           + b[0]*b[0]+b[1]*b[1]+b[2]*b[2]+b[3]*b[3];
  #pragma unroll
  for (int off = 1; off < 64; off <<= 1) ss += __shfl_xor(ss, off, 64);
  __shared__ float sred[4];
  if ((tid & 63) == 0) sred[tid >> 6] = ss;
  __syncthreads();
  const float scale = rsqrtf((sred[0]+sred[1]+sred[2]+sred[3]) * (1.0f/HID) + 1e-6f);
  const float* wp = w + tid * 8;
  f32x4 wa = *(const f32x4*)(wp);
  f32x4 wb = *(const f32x4*)(wp + 4);
  s16x8 o;
  o[0]=f2bf(a[0]*scale*wa[0]); o[1]=f2bf(a[1]*scale*wa[1]);
  o[2]=f2bf(a[2]*scale*wa[2]); o[3]=f2bf(a[3]*scale*wa[3]);
  o[4]=f2bf(b[0]*scale*wb[0]); o[5]=f2bf(b[1]*scale*wb[1]);
  o[6]=f2bf(b[2]*scale*wb[2]); o[7]=f2bf(b[3]*scale*wb[7-4]);
  *(s16x8*)(h + (int64_t)row * HID + tid * 8) = o;
}

// ---------------- GEMM core: C(128x64) = A(128xK) * B(64xK)^T, K=2048 ----
__device__ __forceinline__ void gemm_core_128x64(
    const short* __restrict__ A, const short* __restrict__ B,
    short* sA, short* sB, f32x4 acc[4][2]) {
  const int tid = threadIdx.x;
  const int lane = tid & 63;
  const int w = tid >> 6, wr = w >> 1, wc = w & 1;
  const int g = lane >> 4, li = lane & 15;

  auto stage = [&](int k0, int buf) {
    #pragma unroll
    for (int i = 0; i < 4; ++i) {
      const int flat = i * 256 + tid;      // A: 1024 16B chunks
      const int row = flat >> 3, c8 = flat & 7;
      const int sc = c8 ^ (row & 7);
      gload16(A + (int64_t)row * HID + k0 + sc * 8, sA + buf * 8192 + flat * 8);
    }
    #pragma unroll
    for (int i = 0; i < 2; ++i) {
      const int flat = i * 256 + tid;      // B: 512 16B chunks
      const int row = flat >> 3, c8 = flat & 7;
      const int sc = c8 ^ (row & 7);
      gload16(B + (int64_t)row * HID + k0 + sc * 8, sB + buf * 4096 + flat * 8);
    }
  };

  stage(0, 0);
  for (int k0 = 0; k0 < HID; k0 += 64) {
    const int cur = (k0 >> 6) & 1;
    __syncthreads();                       // cur loads landed; prev buf free
    if (k0 + 64 < HID) stage(k0 + 64, cur ^ 1);
    const short* cA = sA + cur * 8192;
    const short* cB = sB + cur * 4096;
    #pragma unroll
    for (int kk = 0; kk < 2; ++kk) {
      s16x8 af[4], bfr[2];
      const int chunk = (kk << 2) | g;
      #pragma unroll
      for (int m = 0; m < 4; ++m) {
        const int row = wr * 64 + m * 16 + li;
        af[m] = *(const s16x8*)(cA + row * 64 + ((chunk ^ (li & 7)) << 3));
      }
      #pragma unroll
      for (int n = 0; n < 2; ++n) {
        const int row = wc * 32 + n * 16 + li;
        bfr[n] = *(const s16x8*)(cB + row * 64 + ((chunk ^ (li & 7)) << 3));
      }
      __builtin_amdgcn_s_setprio(1);
      #pragma unroll
      for (int m = 0; m < 4; ++m)
        #pragma unroll
        for (int n = 0; n < 2; ++n)
          acc[m][n] = __builtin_amdgcn_mfma_f32_16x16x32_bf16(af[m], bfr[n], acc[m][n], 0, 0, 0);
      __builtin_amdgcn_s_setprio(0);
    }
  }
}

// ---------------- fused QKV projection + RoPE (+ V transpose) ----------------
__global__ __launch_bounds__(256) void qkv_kernel(
    const short* __restrict__ h16, const short* __restrict__ wq,
    const short* __restrict__ wk, const short* __restrict__ wv,
    short* __restrict__ qo, short* __restrict__ ko, short* __restrict__ vto,
    const float* __restrict__ rc, const float* __restrict__ rs) {
  __shared__ short sA[2 * 128 * 64];       // 32 KB
  __shared__ short sB[2 * 64 * 64];        // 16 KB
  const int cb = blockIdx.x, rb = blockIdx.y;
  const short* B; short* out; int colbase, mode; int64_t ldc;
  if (cb < 32)      { B = wq + (int64_t)cb * 64 * HID;        out = qo;  colbase = cb * 64;        mode = 0; ldc = HID;   }
  else if (cb < 40) { B = wk + (int64_t)(cb - 32) * 64 * HID; out = ko;  colbase = (cb - 32) * 64; mode = 0; ldc = KVDIM; }
  else              { B = wv + (int64_t)(cb - 40) * 64 * HID; out = vto; colbase = (cb - 40) * 64; mode = 1; ldc = L_SEQ; }
  const float rsc = (cb < 32) ? QSCALE : 1.0f;

  f32x4 acc[4][2];
  const f32x4 z = {0.f, 0.f, 0.f, 0.f};
  #pragma unroll
  for (int m = 0; m < 4; ++m)
    #pragma unroll
    for (int n = 0; n < 2; ++n) acc[m][n] = z;

  gemm_core_128x64(h16 + (int64_t)rb * 128 * HID, B, sA, sB, acc);

  const int lane = threadIdx.x & 63;
  const int w = threadIdx.x >> 6, wr = w >> 1, wc = w & 1;
  const int g = lane >> 4, li = lane & 15;

  if (mode == 0) {
    #pragma unroll
    for (int m = 0; m < 4; ++m) {
      #pragma unroll
      for (int n = 0; n < 2; ++n) {
        const int col = colbase + wc * 32 + n * 16 + li;
        const int d2 = col & 62;
        #pragma unroll
        for (int r = 0; r < 4; ++r) {
          const int row = rb * 128 + wr * 64 + m * 16 + g * 4 + r;
          const float c = rc[row * 64 + d2] * rsc;
          const float s = rs[row * 64 + d2] * rsc;
          const float v0 = acc[m][n][r];
          const float pr = __shfl_xor(v0, 1, 64);
          const float o = (lane & 1) ? (v0 * c + pr * s) : (v0 * c - pr * s);
          out[(int64_t)row * ldc + col] = f2bf(o);
        }
      }
    }
  } else {
    #pragma unroll
    for (int m = 0; m < 4; ++m) {
      #pragma unroll
      for (int n = 0; n < 2; ++n) {
        const int col = colbase + wc * 32 + n * 16 + li;
        const int row0 = rb * 128 + wr * 64 + m * 16 + g * 4;
        s16x4 pk;
        pk[0] = f2bf(acc[m][n][0]); pk[1] = f2bf(acc[m][n][1]);
        pk[2] = f2bf(acc[m][n][2]); pk[3] = f2bf(acc[m][n][3]);
        *(s16x4*)(out + (int64_t)col * L_SEQ + row0) = pk;
      }
    }
  }
}

// ---------------- causal GQA flash attention (R12 structure) ----------------
// 8 waves = 2 q-blocks of the uniform pair (pi, 31-pi): 33 tiles/block for
// every block (grid-level balance with 2 blocks/CU queue depth). 2-tiles-
// per-barrier double-buffered K/V staging. Blocks x >= 16 instead convert
// Wo f32->bf16 (24 MB HBM traffic overlapped under compute-bound attn).
__global__ __launch_bounds__(512, 4) void attn_kernel(
    const short* __restrict__ q16, const short* __restrict__ k16,
    const short* __restrict__ vt16, short* __restrict__ out16,
    const float* __restrict__ wof, short* __restrict__ wo16o) {
  if (blockIdx.x >= 16) {
    // Wo converter block: 512 thr x 16 elems, fully coalesced, no barriers.
    const int idx = (blockIdx.x - 16) * NHEAD + blockIdx.y;   // 0..511
    const int64_t base = (int64_t)idx * 8192;
    #pragma unroll
    for (int i = 0; i < 4; ++i) {
      const int64_t o = base + i * 2048 + threadIdx.x * 4;
      f32x4 v = *(const f32x4*)(wof + o);
      s16x4 b;
      b[0] = f2bf(v[0]); b[1] = f2bf(v[1]); b[2] = f2bf(v[2]); b[3] = f2bf(v[3]);
      *(s16x4*)(wo16o + o) = b;
    }
    return;
  }
  __shared__ short sK[4 * 64 * 64];       // [buf][slot] 32 KB
  __shared__ short sV[4 * 64 * 64];       // [buf][slot] 32 KB (V^T: [d][kv])
  __shared__ short sP[8][16 * 64];        // 16 KB per-wave P^T / out transpose
  const int pi = blockIdx.x, h = blockIdx.y, kvh = h >> 2;
  const int qbL = pi, qbH = 31 - pi;
  const int tid = threadIdx.x, lane = tid & 63, w = tid >> 6, wl = w & 3;
  const int g = lane >> 4, li = lane & 15;
  const int myqb = (w < 4) ? qbL : qbH;
  short* sPw = &sP[w][0];

  s16x8 qf[2];
  {
    const int qr = myqb * 64 + wl * 16 + li;
    #pragma unroll
    for (int kk = 0; kk < 2; ++kk)
      qf[kk] = *(const s16x8*)(q16 + (int64_t)qr * HID + h * 64 + kk * 32 + g * 8);
  }

  f32x4 acc[4];
  const f32x4 z = {0.f, 0.f, 0.f, 0.f};
  #pragma unroll
  for (int n = 0; n < 4; ++n) acc[n] = z;
  float m = -1e30f, l = 0.f;

  auto stage1 = [&](int t, int buf, int slot) {
    const int kv0 = t * 64;
    const int row = tid >> 3, c8 = tid & 7;   // 512 threads -> 512 chunks each
    const int sc = c8 ^ (row & 7);
    const int off = (buf * 2 + slot) * 4096;
    gload16(k16 + (int64_t)(kv0 + row) * KVDIM + kvh * 64 + sc * 8,
            sK + off + tid * 8);
    gload16(vt16 + (int64_t)(kvh * 64 + row) * L_SEQ + kv0 + sc * 8,
            sV + off + tid * 8);
  };

  stage1(0, 0, 0);
  stage1(1, 0, 1);                         // qbH >= 16, always valid
  for (int tp = 0; 2 * tp <= qbH; ++tp) {
    const int buf = tp & 1;
    __syncthreads();                       // cur pair landed; other buf free
    if (2 * tp + 2 <= qbH) {
      stage1(2 * tp + 2, buf ^ 1, 0);
      const int t3 = 2 * tp + 3;
      stage1(t3 <= qbH ? t3 : t3 - 1, buf ^ 1, 1);  // clamp: safe, unused
    }
    #pragma unroll
    for (int sl = 0; sl < 2; ++sl) {
      const int t = 2 * tp + sl;
      if (t <= qbH && (w >= 4 || t <= qbL)) {
        const short* cK = sK + (buf * 2 + sl) * 4096;
        const short* cV = sV + (buf * 2 + sl) * 4096;

        // S^T = K * Q  (C cols = q = li, rows = kv)
        s16x8 kf[2][4];
        #pragma unroll
        for (int kk = 0; kk < 2; ++kk)
          #pragma unroll
          for (int n = 0; n < 4; ++n)
            kf[kk][n] = *(const s16x8*)(cK + (n * 16 + li) * 64 + ((((kk << 2) | g) ^ (li & 7)) << 3));
        f32x4 s[4];
        #pragma unroll
        for (int n = 0; n < 4; ++n) s[n] = z;
        __builtin_amdgcn_s_setprio(1);
        #pragma unroll
        for (int kk = 0; kk < 2; ++kk)
          #pragma unroll
          for (int n = 0; n < 4; ++n)
            s[n] = __builtin_amdgcn_mfma_f32_16x16x32_bf16(kf[kk][n], qf[kk], s[n], 0, 0, 0);
        __builtin_amdgcn_s_setprio(0);

        // causal mask on diagonal tile
        if (t == myqb) {
          const int ql = wl * 16 + li;
          #pragma unroll
          for (int n = 0; n < 4; ++n)
            #pragma unroll
            for (int r = 0; r < 4; ++r)
              if (n * 16 + g * 4 + r > ql) s[n][r] = -1e30f;
        }

        // online softmax (exp2 domain; Q pre-scaled), defer-max
        float mx = fmaxf(fmaxf(s[0][0], s[0][1]), fmaxf(s[0][2], s[0][3]));
        #pragma unroll
        for (int n = 1; n < 4; ++n)
          mx = fmaxf(mx, fmaxf(fmaxf(s[n][0], s[n][1]), fmaxf(s[n][2], s[n][3])));
        mx = fmaxf(mx, __shfl_xor(mx, 16, 64));
        mx = fmaxf(mx, __shfl_xor(mx, 32, 64));
        if (__any(mx > m + 8.0f)) {
          const float mn = fmaxf(m, mx);
          const float al = __builtin_amdgcn_exp2f(m - mn);
          m = mn;
          l *= al;
          #pragma unroll
          for (int dt = 0; dt < 4; ++dt)
            #pragma unroll
            for (int r = 0; r < 4; ++r) acc[dt][r] *= al;
        }
        float ps = 0.f;
        #pragma unroll
        for (int n = 0; n < 4; ++n) {
          s16x4 pk;
          #pragma unroll
          for (int r = 0; r < 4; ++r) {
            const float p = __builtin_amdgcn_exp2f(s[n][r] - m);
            pk[r] = f2bf(p);
            ps += p;
          }
          *(s16x4*)(sPw + li * 64 + (((n * 2 + (g >> 1)) ^ (li & 7)) << 3) + (g & 1) * 4) = pk;
        }
        ps += __shfl_xor(ps, 16, 64);
        ps += __shfl_xor(ps, 32, 64);
        l += ps;

        // O^T[d][q] += V^T[d][kv] * P^T[kv][q]
        s16x8 vf[2][4];
        #pragma unroll
        for (int kk = 0; kk < 2; ++kk)
          #pragma unroll
          for (int dt = 0; dt < 4; ++dt)
            vf[kk][dt] = *(const s16x8*)(cV + (dt * 16 + li) * 64 + ((((kk << 2) | g) ^ (li & 7)) << 3));
        #pragma unroll
        for (int kk = 0; kk < 2; ++kk) {
          s16x8 pf = *(const s16x8*)(sPw + li * 64 + (((kk * 4 + g) ^ (li & 7)) << 3));
          __builtin_amdgcn_s_setprio(1);
          #pragma unroll
          for (int dt = 0; dt < 4; ++dt)
            acc[dt] = __builtin_amdgcn_mfma_f32_16x16x32_bf16(vf[kk][dt], pf, acc[dt], 0, 0, 0);
          __builtin_amdgcn_s_setprio(0);
        }
      }
    }
  }

  // normalize, per-wave transpose via sPw, coalesced 16B stores
  const float rl = 1.0f / l;
  #pragma unroll
  for (int n2 = 0; n2 < 4; ++n2) {
    s16x4 o;
    #pragma unroll
    for (int r = 0; r < 4; ++r) o[r] = f2bf(acc[n2][r] * rl);
    *(s16x4*)(sPw + li * 64 + (((n2 * 2 + (g >> 1)) ^ (li & 7)) << 3) + (g & 1) * 4) = o;
  }
  #pragma unroll
  for (int half = 0; half < 2; ++half) {
    const int chunk = half * 64 + lane;
    const int q = chunk >> 3, c = chunk & 7;
    s16x8 v = *(const s16x8*)(sPw + q * 64 + ((c ^ (q & 7)) << 3));
    *(s16x8*)(out16 + (int64_t)(myqb * 64 + wl * 16 + q) * HID + h * 64 + c * 8) = v;
  }
}

// ---------------- O projection + residual ----------------
__global__ __launch_bounds__(256) void oproj_kernel(
    const short* __restrict__ ao, const short* __restrict__ wo,
    const float* __restrict__ resid, float* __restrict__ out) {
  __shared__ short sA[2 * 128 * 64];
  __shared__ short sB[2 * 64 * 64];
  const int cb = blockIdx.x, rb = blockIdx.y;
  f32x4 acc[4][2];
  const f32x4 z = {0.f, 0.f, 0.f, 0.f};
  #pragma unroll
  for (int m = 0; m < 4; ++m)
    #pragma unroll
    for (int n = 0; n < 2; ++n) acc[m][n] = z;

  gemm_core_128x64(ao + (int64_t)rb * 128 * HID, wo + (int64_t)cb * 64 * HID, sA, sB, acc);

  const int lane = threadIdx.x & 63;
  const int w = threadIdx.x >> 6, wr = w >> 1, wc = w & 1;
  const int g = lane >> 4, li = lane & 15;
  #pragma unroll
  for (int m = 0; m < 4; ++m) {
    #pragma unroll
    for (int n = 0; n < 2; ++n) {
      const int col = cb * 64 + wc * 32 + n * 16 + li;
      #pragma unroll
      for (int r = 0; r < 4; ++r) {
        const int row = rb * 128 + wr * 64 + m * 16 + g * 4 + r;
        out[(int64_t)row * HID + col] = acc[m][n][r] + resid[(int64_t)row * HID + col];
      }
    }
  }
}

extern "C" void kernel_launch(void* const* d_in, const int* in_sizes, int n_in,
                              void* d_out, int out_size, void* d_ws, size_t ws_size,
                              hipStream_t stream) {
  (void)in_sizes; (void)n_in; (void)out_size; (void)ws_size;
  const float* x      = (const float*)d_in[0];
  const float* norm_w = (const float*)d_in[2];
  const float* Wq     = (const float*)d_in[3];
  const float* Wk     = (const float*)d_in[4];
  const float* Wv     = (const float*)d_in[5];
  const float* Wo     = (const float*)d_in[6];
  const float* rc     = (const float*)d_in[7];
  const float* rs     = (const float*)d_in[8];
  float* out = (float*)d_out;

  char* ws = (char*)d_ws;
  short* wq16 = (short*)(ws);
  short* wk16 = (short*)(ws + 8388608);
  short* wv16 = (short*)(ws + 10485760);
  short* wo16 = (short*)(ws + 12582912);
  short* h16  = (short*)(ws + 20971520);
  short* q16  = (short*)(ws + 29360128);
  short* k16  = (short*)(ws + 37748736);
  short* vt16 = (short*)(ws + 39845888);
  short* ao16 = (short*)(ws + 41943040);

  pre_kernel<<<8192, 256, 0, stream>>>(x, norm_w, Wq, Wk, Wv,
                                       h16, wq16, wk16, wv16);
  qkv_kernel<<<dim3(48, 16), 256, 0, stream>>>(h16, wq16, wk16, wv16, q16, k16, vt16, rc, rs);
  attn_kernel<<<dim3(32, NHEAD), 512, 0, stream>>>(q16, k16, vt16, ao16, Wo, wo16);
  oproj_kernel<<<dim3(32, 16), 256, 0, stream>>>(ao16, wo16, x, out);
}

// Round 16
// 123.847 us; speedup vs baseline: 1.2663x; 1.2663x over previous
//
#include <hip/hip_runtime.h>
#include <stdint.h>

#define L_SEQ 2048
#define HID   2048
#define NHEAD 32
#define NKV   8
#define HD    64
#define KVDIM 512
#define QSCALE 0.18033688f         /* log2(e)/8 folded into Q at projection */

typedef __attribute__((ext_vector_type(8))) short s16x8;
typedef __attribute__((ext_vector_type(4))) short s16x4;
typedef __attribute__((ext_vector_type(4))) float f32x4;

// native RNE f32->bf16 (v_cvt_pk_bf16_f32 on gfx950)
__device__ __forceinline__ short f2bf(float f) {
  __bf16 b = (__bf16)f;
  short s;
  __builtin_memcpy(&s, &b, 2);
  return s;
}

// async global->LDS, 16B/lane. Linear LDS dest + inverse-swizzled global
// source + swizzled read (rule #21).
__device__ __forceinline__ void gload16(const void* g, void* l) {
  __builtin_amdgcn_global_load_lds(
      (const __attribute__((address_space(1))) void*)g,
      (__attribute__((address_space(3))) void*)l, 16, 0, 0);
}

// ---------------- fused weight-convert + RMSNorm (one launch) ----------------
__global__ __launch_bounds__(256) void pre_kernel(
    const float* __restrict__ x, const float* __restrict__ w,
    const float* __restrict__ wq, const float* __restrict__ wk,
    const float* __restrict__ wv, const float* __restrict__ wo,
    short* __restrict__ h,
    short* __restrict__ owq, short* __restrict__ owk,
    short* __restrict__ owv, short* __restrict__ owo) {
  const int tid = threadIdx.x;
  if (blockIdx.x >= 2048) {
    int64_t e = ((int64_t)(blockIdx.x - 2048) * 256 + tid) * 4;
    const float* src; short* dst; int64_t o;
    if (e < 4194304)      { src = wq; dst = owq; o = e; }
    else if (e < 5242880) { src = wk; dst = owk; o = e - 4194304; }
    else if (e < 6291456) { src = wv; dst = owv; o = e - 5242880; }
    else                  { src = wo; dst = owo; o = e - 6291456; }
    f32x4 v = *(const f32x4*)(src + o);
    s16x4 b;
    b[0] = f2bf(v[0]); b[1] = f2bf(v[1]); b[2] = f2bf(v[2]); b[3] = f2bf(v[3]);
    *(s16x4*)(dst + o) = b;
    return;
  }
  const int row = blockIdx.x;
  const float* xr = x + (int64_t)row * HID + tid * 8;
  f32x4 a = *(const f32x4*)(xr);
  f32x4 b = *(const f32x4*)(xr + 4);
  float ss = a[0]*a[0]+a[1]*a[1]+a[2]*a[2]+a[3]*a[3]
           + b[0]*b[0]+b[1]*b[1]+b[2]*b[2]+b[3]*b[3];
  #pragma unroll
  for (int off = 1; off < 64; off <<= 1) ss += __shfl_xor(ss, off, 64);
  __shared__ float sred[4];
  if ((tid & 63) == 0) sred[tid >> 6] = ss;
  __syncthreads();
  const float scale = rsqrtf((sred[0]+sred[1]+sred[2]+sred[3]) * (1.0f/HID) + 1e-6f);
  const float* wp = w + tid * 8;
  f32x4 wa = *(const f32x4*)(wp);
  f32x4 wb = *(const f32x4*)(wp + 4);
  s16x8 o;
  o[0]=f2bf(a[0]*scale*wa[0]); o[1]=f2bf(a[1]*scale*wa[1]);
  o[2]=f2bf(a[2]*scale*wa[2]); o[3]=f2bf(a[3]*scale*wa[3]);
  o[4]=f2bf(b[0]*scale*wb[0]); o[5]=f2bf(b[1]*scale*wb[1]);
  o[6]=f2bf(b[2]*scale*wb[2]); o[7]=f2bf(b[3]*scale*wb[3]);
  *(s16x8*)(h + (int64_t)row * HID + tid * 8) = o;
}

// ---------------- GEMM core: C(128x64) = A(128xK) * B(64xK)^T, K=2048 ----
__device__ __forceinline__ void gemm_core_128x64(
    const short* __restrict__ A, const short* __restrict__ B,
    short* sA, short* sB, f32x4 acc[4][2]) {
  const int tid = threadIdx.x;
  const int lane = tid & 63;
  const int w = tid >> 6, wr = w >> 1, wc = w & 1;
  const int g = lane >> 4, li = lane & 15;

  auto stage = [&](int k0, int buf) {
    #pragma unroll
    for (int i = 0; i < 4; ++i) {
      const int flat = i * 256 + tid;      // A: 1024 16B chunks
      const int row = flat >> 3, c8 = flat & 7;
      const int sc = c8 ^ (row & 7);
      gload16(A + (int64_t)row * HID + k0 + sc * 8, sA + buf * 8192 + flat * 8);
    }
    #pragma unroll
    for (int i = 0; i < 2; ++i) {
      const int flat = i * 256 + tid;      // B: 512 16B chunks
      const int row = flat >> 3, c8 = flat & 7;
      const int sc = c8 ^ (row & 7);
      gload16(B + (int64_t)row * HID + k0 + sc * 8, sB + buf * 4096 + flat * 8);
    }
  };

  stage(0, 0);
  for (int k0 = 0; k0 < HID; k0 += 64) {
    const int cur = (k0 >> 6) & 1;
    __syncthreads();                       // cur loads landed; prev buf free
    if (k0 + 64 < HID) stage(k0 + 64, cur ^ 1);
    const short* cA = sA + cur * 8192;
    const short* cB = sB + cur * 4096;
    #pragma unroll
    for (int kk = 0; kk < 2; ++kk) {
      s16x8 af[4], bfr[2];
      const int chunk = (kk << 2) | g;
      #pragma unroll
      for (int m = 0; m < 4; ++m) {
        const int row = wr * 64 + m * 16 + li;
        af[m] = *(const s16x8*)(cA + row * 64 + ((chunk ^ (li & 7)) << 3));
      }
      #pragma unroll
      for (int n = 0; n < 2; ++n) {
        const int row = wc * 32 + n * 16 + li;
        bfr[n] = *(const s16x8*)(cB + row * 64 + ((chunk ^ (li & 7)) << 3));
      }
      __builtin_amdgcn_s_setprio(1);
      #pragma unroll
      for (int m = 0; m < 4; ++m)
        #pragma unroll
        for (int n = 0; n < 2; ++n)
          acc[m][n] = __builtin_amdgcn_mfma_f32_16x16x32_bf16(af[m], bfr[n], acc[m][n], 0, 0, 0);
      __builtin_amdgcn_s_setprio(0);
    }
  }
}

// ---------------- fused QKV projection + RoPE (+ V transpose) ----------------
__global__ __launch_bounds__(256) void qkv_kernel(
    const short* __restrict__ h16, const short* __restrict__ wq,
    const short* __restrict__ wk, const short* __restrict__ wv,
    short* __restrict__ qo, short* __restrict__ ko, short* __restrict__ vto,
    const float* __restrict__ rc, const float* __restrict__ rs) {
  __shared__ short sA[2 * 128 * 64];       // 32 KB
  __shared__ short sB[2 * 64 * 64];        // 16 KB
  const int cb = blockIdx.x, rb = blockIdx.y;
  const short* B; short* out; int colbase, mode; int64_t ldc;
  if (cb < 32)      { B = wq + (int64_t)cb * 64 * HID;        out = qo;  colbase = cb * 64;        mode = 0; ldc = HID;   }
  else if (cb < 40) { B = wk + (int64_t)(cb - 32) * 64 * HID; out = ko;  colbase = (cb - 32) * 64; mode = 0; ldc = KVDIM; }
  else              { B = wv + (int64_t)(cb - 40) * 64 * HID; out = vto; colbase = (cb - 40) * 64; mode = 1; ldc = L_SEQ; }
  const float rsc = (cb < 32) ? QSCALE : 1.0f;

  f32x4 acc[4][2];
  const f32x4 z = {0.f, 0.f, 0.f, 0.f};
  #pragma unroll
  for (int m = 0; m < 4; ++m)
    #pragma unroll
    for (int n = 0; n < 2; ++n) acc[m][n] = z;

  gemm_core_128x64(h16 + (int64_t)rb * 128 * HID, B, sA, sB, acc);

  const int lane = threadIdx.x & 63;
  const int w = threadIdx.x >> 6, wr = w >> 1, wc = w & 1;
  const int g = lane >> 4, li = lane & 15;

  if (mode == 0) {
    #pragma unroll
    for (int m = 0; m < 4; ++m) {
      #pragma unroll
      for (int n = 0; n < 2; ++n) {
        const int col = colbase + wc * 32 + n * 16 + li;
        const int d2 = col & 62;
        #pragma unroll
        for (int r = 0; r < 4; ++r) {
          const int row = rb * 128 + wr * 64 + m * 16 + g * 4 + r;
          const float c = rc[row * 64 + d2] * rsc;
          const float s = rs[row * 64 + d2] * rsc;
          const float v0 = acc[m][n][r];
          const float pr = __shfl_xor(v0, 1, 64);
          const float o = (lane & 1) ? (v0 * c + pr * s) : (v0 * c - pr * s);
          out[(int64_t)row * ldc + col] = f2bf(o);
        }
      }
    }
  } else {
    #pragma unroll
    for (int m = 0; m < 4; ++m) {
      #pragma unroll
      for (int n = 0; n < 2; ++n) {
        const int col = colbase + wc * 32 + n * 16 + li;
        const int row0 = rb * 128 + wr * 64 + m * 16 + g * 4;
        s16x4 pk;
        pk[0] = f2bf(acc[m][n][0]); pk[1] = f2bf(acc[m][n][1]);
        pk[2] = f2bf(acc[m][n][2]); pk[3] = f2bf(acc[m][n][3]);
        *(s16x4*)(out + (int64_t)col * L_SEQ + row0) = pk;
      }
    }
  }
}

// ---------------- causal GQA flash attention (R12 structure) ----------------
// 8 waves = 2 q-blocks of the uniform pair (pi, 31-pi): 33 tiles for every
// block (grid-level balance, 512 blocks = 2/CU). 2-tiles-per-barrier dbuf
// K/V staging. vf loads hoisted ABOVE the softmax so LDS latency drains
// under the VALU chain (addresses independent of softmax results).
__global__ __launch_bounds__(512, 4) void attn_kernel(
    const short* __restrict__ q16, const short* __restrict__ k16,
    const short* __restrict__ vt16, short* __restrict__ out16) {
  __shared__ short sK[4 * 64 * 64];       // [buf][slot] 32 KB
  __shared__ short sV[4 * 64 * 64];       // [buf][slot] 32 KB (V^T: [d][kv])
  __shared__ short sP[8][16 * 64];        // 16 KB per-wave P^T / out transpose
  const int pi = blockIdx.x, h = blockIdx.y, kvh = h >> 2;
  const int qbL = pi, qbH = 31 - pi;
  const int tid = threadIdx.x, lane = tid & 63, w = tid >> 6, wl = w & 3;
  const int g = lane >> 4, li = lane & 15;
  const int myqb = (w < 4) ? qbL : qbH;
  short* sPw = &sP[w][0];

  s16x8 qf[2];
  {
    const int qr = myqb * 64 + wl * 16 + li;
    #pragma unroll
    for (int kk = 0; kk < 2; ++kk)
      qf[kk] = *(const s16x8*)(q16 + (int64_t)qr * HID + h * 64 + kk * 32 + g * 8);
  }

  f32x4 acc[4];
  const f32x4 z = {0.f, 0.f, 0.f, 0.f};
  #pragma unroll
  for (int n = 0; n < 4; ++n) acc[n] = z;
  float m = -1e30f, l = 0.f;

  auto stage1 = [&](int t, int buf, int slot) {
    const int kv0 = t * 64;
    const int row = tid >> 3, c8 = tid & 7;   // 512 threads -> 512 chunks each
    const int sc = c8 ^ (row & 7);
    const int off = (buf * 2 + slot) * 4096;
    gload16(k16 + (int64_t)(kv0 + row) * KVDIM + kvh * 64 + sc * 8,
            sK + off + tid * 8);
    gload16(vt16 + (int64_t)(kvh * 64 + row) * L_SEQ + kv0 + sc * 8,
            sV + off + tid * 8);
  };

  stage1(0, 0, 0);
  stage1(1, 0, 1);                         // qbH >= 16, always valid
  for (int tp = 0; 2 * tp <= qbH; ++tp) {
    const int buf = tp & 1;
    __syncthreads();                       // cur pair landed; other buf free
    if (2 * tp + 2 <= qbH) {
      stage1(2 * tp + 2, buf ^ 1, 0);
      const int t3 = 2 * tp + 3;
      stage1(t3 <= qbH ? t3 : t3 - 1, buf ^ 1, 1);  // clamp: safe, unused
    }
    #pragma unroll
    for (int sl = 0; sl < 2; ++sl) {
      const int t = 2 * tp + sl;
      if (t <= qbH && (w >= 4 || t <= qbL)) {
        const short* cK = sK + (buf * 2 + sl) * 4096;
        const short* cV = sV + (buf * 2 + sl) * 4096;

        // S^T = K * Q  (C cols = q = li, rows = kv)
        s16x8 kf[2][4];
        #pragma unroll
        for (int kk = 0; kk < 2; ++kk)
          #pragma unroll
          for (int n = 0; n < 4; ++n)
            kf[kk][n] = *(const s16x8*)(cK + (n * 16 + li) * 64 + ((((kk << 2) | g) ^ (li & 7)) << 3));
        f32x4 s[4];
        #pragma unroll
        for (int n = 0; n < 4; ++n) s[n] = z;
        __builtin_amdgcn_s_setprio(1);
        #pragma unroll
        for (int kk = 0; kk < 2; ++kk)
          #pragma unroll
          for (int n = 0; n < 4; ++n)
            s[n] = __builtin_amdgcn_mfma_f32_16x16x32_bf16(kf[kk][n], qf[kk], s[n], 0, 0, 0);
        __builtin_amdgcn_s_setprio(0);

        // V^T fragments hoisted here: ds_read latency drains under softmax
        s16x8 vf[2][4];
        #pragma unroll
        for (int kk = 0; kk < 2; ++kk)
          #pragma unroll
          for (int dt = 0; dt < 4; ++dt)
            vf[kk][dt] = *(const s16x8*)(cV + (dt * 16 + li) * 64 + ((((kk << 2) | g) ^ (li & 7)) << 3));

        // causal mask on diagonal tile
        if (t == myqb) {
          const int ql = wl * 16 + li;
          #pragma unroll
          for (int n = 0; n < 4; ++n)
            #pragma unroll
            for (int r = 0; r < 4; ++r)
              if (n * 16 + g * 4 + r > ql) s[n][r] = -1e30f;
        }

        // online softmax (exp2 domain; Q pre-scaled), defer-max
        float mx = fmaxf(fmaxf(s[0][0], s[0][1]), fmaxf(s[0][2], s[0][3]));
        #pragma unroll
        for (int n = 1; n < 4; ++n)
          mx = fmaxf(mx, fmaxf(fmaxf(s[n][0], s[n][1]), fmaxf(s[n][2], s[n][3])));
        mx = fmaxf(mx, __shfl_xor(mx, 16, 64));
        mx = fmaxf(mx, __shfl_xor(mx, 32, 64));
        if (__any(mx > m + 8.0f)) {
          const float mn = fmaxf(m, mx);
          const float al = __builtin_amdgcn_exp2f(m - mn);
          m = mn;
          l *= al;
          #pragma unroll
          for (int dt = 0; dt < 4; ++dt)
            #pragma unroll
            for (int r = 0; r < 4; ++r) acc[dt][r] *= al;
        }
        float ps = 0.f;
        #pragma unroll
        for (int n = 0; n < 4; ++n) {
          s16x4 pk;
          #pragma unroll
          for (int r = 0; r < 4; ++r) {
            const float p = __builtin_amdgcn_exp2f(s[n][r] - m);
            pk[r] = f2bf(p);
            ps += p;
          }
          *(s16x4*)(sPw + li * 64 + (((n * 2 + (g >> 1)) ^ (li & 7)) << 3) + (g & 1) * 4) = pk;
        }
        ps += __shfl_xor(ps, 16, 64);
        ps += __shfl_xor(ps, 32, 64);
        l += ps;

        // O^T[d][q] += V^T[d][kv] * P^T[kv][q]
        #pragma unroll
        for (int kk = 0; kk < 2; ++kk) {
          s16x8 pf = *(const s16x8*)(sPw + li * 64 + (((kk * 4 + g) ^ (li & 7)) << 3));
          __builtin_amdgcn_s_setprio(1);
          #pragma unroll
          for (int dt = 0; dt < 4; ++dt)
            acc[dt] = __builtin_amdgcn_mfma_f32_16x16x32_bf16(vf[kk][dt], pf, acc[dt], 0, 0, 0);
          __builtin_amdgcn_s_setprio(0);
        }
      }
    }
  }

  // normalize, per-wave transpose via sPw, coalesced 16B stores
  const float rl = 1.0f / l;
  #pragma unroll
  for (int n2 = 0; n2 < 4; ++n2) {
    s16x4 o;
    #pragma unroll
    for (int r = 0; r < 4; ++r) o[r] = f2bf(acc[n2][r] * rl);
    *(s16x4*)(sPw + li * 64 + (((n2 * 2 + (g >> 1)) ^ (li & 7)) << 3) + (g & 1) * 4) = o;
  }
  #pragma unroll
  for (int half = 0; half < 2; ++half) {
    const int chunk = half * 64 + lane;
    const int q = chunk >> 3, c = chunk & 7;
    s16x8 v = *(const s16x8*)(sPw + q * 64 + ((c ^ (q & 7)) << 3));
    *(s16x8*)(out16 + (int64_t)(myqb * 64 + wl * 16 + q) * HID + h * 64 + c * 8) = v;
  }
}

// ---------------- O projection + residual ----------------
__global__ __launch_bounds__(256) void oproj_kernel(
    const short* __restrict__ ao, const short* __restrict__ wo,
    const float* __restrict__ resid, float* __restrict__ out) {
  __shared__ short sA[2 * 128 * 64];
  __shared__ short sB[2 * 64 * 64];
  const int cb = blockIdx.x, rb = blockIdx.y;
  f32x4 acc[4][2];
  const f32x4 z = {0.f, 0.f, 0.f, 0.f};
  #pragma unroll
  for (int m = 0; m < 4; ++m)
    #pragma unroll
    for (int n = 0; n < 2; ++n) acc[m][n] = z;

  gemm_core_128x64(ao + (int64_t)rb * 128 * HID, wo + (int64_t)cb * 64 * HID, sA, sB, acc);

  const int lane = threadIdx.x & 63;
  const int w = threadIdx.x >> 6, wr = w >> 1, wc = w & 1;
  const int g = lane >> 4, li = lane & 15;
  #pragma unroll
  for (int m = 0; m < 4; ++m) {
    #pragma unroll
    for (int n = 0; n < 2; ++n) {
      const int col = cb * 64 + wc * 32 + n * 16 + li;
      #pragma unroll
      for (int r = 0; r < 4; ++r) {
        const int row = rb * 128 + wr * 64 + m * 16 + g * 4 + r;
        out[(int64_t)row * HID + col] = acc[m][n][r] + resid[(int64_t)row * HID + col];
      }
    }
  }
}

extern "C" void kernel_launch(void* const* d_in, const int* in_sizes, int n_in,
                              void* d_out, int out_size, void* d_ws, size_t ws_size,
                              hipStream_t stream) {
  (void)in_sizes; (void)n_in; (void)out_size; (void)ws_size;
  const float* x      = (const float*)d_in[0];
  const float* norm_w = (const float*)d_in[2];
  const float* Wq     = (const float*)d_in[3];
  const float* Wk     = (const float*)d_in[4];
  const float* Wv     = (const float*)d_in[5];
  const float* Wo     = (const float*)d_in[6];
  const float* rc     = (const float*)d_in[7];
  const float* rs     = (const float*)d_in[8];
  float* out = (float*)d_out;

  char* ws = (char*)d_ws;
  short* wq16 = (short*)(ws);
  short* wk16 = (short*)(ws + 8388608);
  short* wv16 = (short*)(ws + 10485760);
  short* wo16 = (short*)(ws + 12582912);
  short* h16  = (short*)(ws + 20971520);
  short* q16  = (short*)(ws + 29360128);
  short* k16  = (short*)(ws + 37748736);
  short* vt16 = (short*)(ws + 39845888);
  short* ao16 = (short*)(ws + 41943040);

  pre_kernel<<<12288, 256, 0, stream>>>(x, norm_w, Wq, Wk, Wv, Wo,
                                        h16, wq16, wk16, wv16, wo16);
  qkv_kernel<<<dim3(48, 16), 256, 0, stream>>>(h16, wq16, wk16, wv16, q16, k16, vt16, rc, rs);
  attn_kernel<<<dim3(16, NHEAD), 512, 0, stream>>>(q16, k16, vt16, ao16);
  oproj_kernel<<<dim3(32, 16), 256, 0, stream>>>(ao16, wo16, x, out);
}

// Round 17
// 121.423 us; speedup vs baseline: 1.2916x; 1.0200x over previous
//
#include <hip/hip_runtime.h>
#include <stdint.h>

#define L_SEQ 2048
#define HID   2048
#define NHEAD 32
#define NKV   8
#define HD    64
#define KVDIM 512
#define QSCALE 0.18033688f         /* log2(e)/8 folded into Q at projection */

typedef __attribute__((ext_vector_type(8))) short s16x8;
typedef __attribute__((ext_vector_type(4))) short s16x4;
typedef __attribute__((ext_vector_type(4))) float f32x4;

// native RNE f32->bf16 (v_cvt_pk_bf16_f32 on gfx950)
__device__ __forceinline__ short f2bf(float f) {
  __bf16 b = (__bf16)f;
  short s;
  __builtin_memcpy(&s, &b, 2);
  return s;
}

// async global->LDS, 16B/lane. Linear LDS dest + inverse-swizzled global
// source + swizzled read (rule #21).
__device__ __forceinline__ void gload16(const void* g, void* l) {
  __builtin_amdgcn_global_load_lds(
      (const __attribute__((address_space(1))) void*)g,
      (__attribute__((address_space(3))) void*)l, 16, 0, 0);
}

// ---------------- fused weight-convert + RMSNorm (one launch) ----------------
__global__ __launch_bounds__(256) void pre_kernel(
    const float* __restrict__ x, const float* __restrict__ w,
    const float* __restrict__ wq, const float* __restrict__ wk,
    const float* __restrict__ wv, const float* __restrict__ wo,
    short* __restrict__ h,
    short* __restrict__ owq, short* __restrict__ owk,
    short* __restrict__ owv, short* __restrict__ owo) {
  const int tid = threadIdx.x;
  if (blockIdx.x >= 2048) {
    int64_t e = ((int64_t)(blockIdx.x - 2048) * 256 + tid) * 4;
    const float* src; short* dst; int64_t o;
    if (e < 4194304)      { src = wq; dst = owq; o = e; }
    else if (e < 5242880) { src = wk; dst = owk; o = e - 4194304; }
    else if (e < 6291456) { src = wv; dst = owv; o = e - 5242880; }
    else                  { src = wo; dst = owo; o = e - 6291456; }
    f32x4 v = *(const f32x4*)(src + o);
    s16x4 b;
    b[0] = f2bf(v[0]); b[1] = f2bf(v[1]); b[2] = f2bf(v[2]); b[3] = f2bf(v[3]);
    *(s16x4*)(dst + o) = b;
    return;
  }
  const int row = blockIdx.x;
  const float* xr = x + (int64_t)row * HID + tid * 8;
  f32x4 a = *(const f32x4*)(xr);
  f32x4 b = *(const f32x4*)(xr + 4);
  float ss = a[0]*a[0]+a[1]*a[1]+a[2]*a[2]+a[3]*a[3]
           + b[0]*b[0]+b[1]*b[1]+b[2]*b[2]+b[3]*b[3];
  #pragma unroll
  for (int off = 1; off < 64; off <<= 1) ss += __shfl_xor(ss, off, 64);
  __shared__ float sred[4];
  if ((tid & 63) == 0) sred[tid >> 6] = ss;
  __syncthreads();
  const float scale = rsqrtf((sred[0]+sred[1]+sred[2]+sred[3]) * (1.0f/HID) + 1e-6f);
  const float* wp = w + tid * 8;
  f32x4 wa = *(const f32x4*)(wp);
  f32x4 wb = *(const f32x4*)(wp + 4);
  s16x8 o;
  o[0]=f2bf(a[0]*scale*wa[0]); o[1]=f2bf(a[1]*scale*wa[1]);
  o[2]=f2bf(a[2]*scale*wa[2]); o[3]=f2bf(a[3]*scale*wa[3]);
  o[4]=f2bf(b[0]*scale*wb[0]); o[5]=f2bf(b[1]*scale*wb[1]);
  o[6]=f2bf(b[2]*scale*wb[2]); o[7]=f2bf(b[3]*scale*wb[3]);
  *(s16x8*)(h + (int64_t)row * HID + tid * 8) = o;
}

// ---------------- GEMM core: C(128x64) = A(128xK) * B(64xK)^T, K=2048 ----
__device__ __forceinline__ void gemm_core_128x64(
    const short* __restrict__ A, const short* __restrict__ B,
    short* sA, short* sB, f32x4 acc[4][2]) {
  const int tid = threadIdx.x;
  const int lane = tid & 63;
  const int w = tid >> 6, wr = w >> 1, wc = w & 1;
  const int g = lane >> 4, li = lane & 15;

  auto stage = [&](int k0, int buf) {
    #pragma unroll
    for (int i = 0; i < 4; ++i) {
      const int flat = i * 256 + tid;      // A: 1024 16B chunks
      const int row = flat >> 3, c8 = flat & 7;
      const int sc = c8 ^ (row & 7);
      gload16(A + (int64_t)row * HID + k0 + sc * 8, sA + buf * 8192 + flat * 8);
    }
    #pragma unroll
    for (int i = 0; i < 2; ++i) {
      const int flat = i * 256 + tid;      // B: 512 16B chunks
      const int row = flat >> 3, c8 = flat & 7;
      const int sc = c8 ^ (row & 7);
      gload16(B + (int64_t)row * HID + k0 + sc * 8, sB + buf * 4096 + flat * 8);
    }
  };

  stage(0, 0);
  for (int k0 = 0; k0 < HID; k0 += 64) {
    const int cur = (k0 >> 6) & 1;
    __syncthreads();                       // cur loads landed; prev buf free
    if (k0 + 64 < HID) stage(k0 + 64, cur ^ 1);
    const short* cA = sA + cur * 8192;
    const short* cB = sB + cur * 4096;
    #pragma unroll
    for (int kk = 0; kk < 2; ++kk) {
      s16x8 af[4], bfr[2];
      const int chunk = (kk << 2) | g;
      #pragma unroll
      for (int m = 0; m < 4; ++m) {
        const int row = wr * 64 + m * 16 + li;
        af[m] = *(const s16x8*)(cA + row * 64 + ((chunk ^ (li & 7)) << 3));
      }
      #pragma unroll
      for (int n = 0; n < 2; ++n) {
        const int row = wc * 32 + n * 16 + li;
        bfr[n] = *(const s16x8*)(cB + row * 64 + ((chunk ^ (li & 7)) << 3));
      }
      __builtin_amdgcn_s_setprio(1);
      #pragma unroll
      for (int m = 0; m < 4; ++m)
        #pragma unroll
        for (int n = 0; n < 2; ++n)
          acc[m][n] = __builtin_amdgcn_mfma_f32_16x16x32_bf16(af[m], bfr[n], acc[m][n], 0, 0, 0);
      __builtin_amdgcn_s_setprio(0);
    }
  }
}

// ---------------- fused QKV projection + RoPE (+ V transpose) ----------------
__global__ __launch_bounds__(256) void qkv_kernel(
    const short* __restrict__ h16, const short* __restrict__ wq,
    const short* __restrict__ wk, const short* __restrict__ wv,
    short* __restrict__ qo, short* __restrict__ ko, short* __restrict__ vto,
    const float* __restrict__ rc, const float* __restrict__ rs) {
  __shared__ short sA[2 * 128 * 64];       // 32 KB
  __shared__ short sB[2 * 64 * 64];        // 16 KB
  const int cb = blockIdx.x, rb = blockIdx.y;
  const short* B; short* out; int colbase, mode; int64_t ldc;
  if (cb < 32)      { B = wq + (int64_t)cb * 64 * HID;        out = qo;  colbase = cb * 64;        mode = 0; ldc = HID;   }
  else if (cb < 40) { B = wk + (int64_t)(cb - 32) * 64 * HID; out = ko;  colbase = (cb - 32) * 64; mode = 0; ldc = KVDIM; }
  else              { B = wv + (int64_t)(cb - 40) * 64 * HID; out = vto; colbase = (cb - 40) * 64; mode = 1; ldc = L_SEQ; }
  const float rsc = (cb < 32) ? QSCALE : 1.0f;

  f32x4 acc[4][2];
  const f32x4 z = {0.f, 0.f, 0.f, 0.f};
  #pragma unroll
  for (int m = 0; m < 4; ++m)
    #pragma unroll
    for (int n = 0; n < 2; ++n) acc[m][n] = z;

  gemm_core_128x64(h16 + (int64_t)rb * 128 * HID, B, sA, sB, acc);

  const int lane = threadIdx.x & 63;
  const int w = threadIdx.x >> 6, wr = w >> 1, wc = w & 1;
  const int g = lane >> 4, li = lane & 15;

  if (mode == 0) {
    #pragma unroll
    for (int m = 0; m < 4; ++m) {
      #pragma unroll
      for (int n = 0; n < 2; ++n) {
        const int col = colbase + wc * 32 + n * 16 + li;
        const int d2 = col & 62;
        #pragma unroll
        for (int r = 0; r < 4; ++r) {
          const int row = rb * 128 + wr * 64 + m * 16 + g * 4 + r;
          const float c = rc[row * 64 + d2] * rsc;
          const float s = rs[row * 64 + d2] * rsc;
          const float v0 = acc[m][n][r];
          const float pr = __shfl_xor(v0, 1, 64);
          const float o = (lane & 1) ? (v0 * c + pr * s) : (v0 * c - pr * s);
          out[(int64_t)row * ldc + col] = f2bf(o);
        }
      }
    }
  } else {
    #pragma unroll
    for (int m = 0; m < 4; ++m) {
      #pragma unroll
      for (int n = 0; n < 2; ++n) {
        const int col = colbase + wc * 32 + n * 16 + li;
        const int row0 = rb * 128 + wr * 64 + m * 16 + g * 4;
        s16x4 pk;
        pk[0] = f2bf(acc[m][n][0]); pk[1] = f2bf(acc[m][n][1]);
        pk[2] = f2bf(acc[m][n][2]); pk[3] = f2bf(acc[m][n][3]);
        *(s16x4*)(out + (int64_t)col * L_SEQ + row0) = pk;
      }
    }
  }
}

// ---------------- causal GQA flash attention (R12 structure) ----------------
// 8 waves = 2 q-blocks of the uniform pair (pi, 31-pi). 2-tiles-per-barrier
// dbuf staging with pointer-incremented addresses. COMBINED softmax across
// the 2-tile batch: one max-reduce, one defer-max rescale, one ps-reduce per
// pair (valid online softmax with the joint max). Deterministic.
__global__ __launch_bounds__(512, 4) void attn_kernel(
    const short* __restrict__ q16, const short* __restrict__ k16,
    const short* __restrict__ vt16, short* __restrict__ out16) {
  __shared__ short sK[4 * 64 * 64];       // [buf][slot] 32 KB
  __shared__ short sV[4 * 64 * 64];       // [buf][slot] 32 KB (V^T: [d][kv])
  __shared__ short sP[8][16 * 64];        // 16 KB per-wave P^T / out transpose
  const int pi = blockIdx.x, h = blockIdx.y, kvh = h >> 2;
  const int qbL = pi, qbH = 31 - pi;
  const int tid = threadIdx.x, lane = tid & 63, w = tid >> 6, wl = w & 3;
  const int g = lane >> 4, li = lane & 15;
  const int myqb = (w < 4) ? qbL : qbH;
  short* sPw = &sP[w][0];

  s16x8 qf[2];
  {
    const int qr = myqb * 64 + wl * 16 + li;
    #pragma unroll
    for (int kk = 0; kk < 2; ++kk)
      qf[kk] = *(const s16x8*)(q16 + (int64_t)qr * HID + h * 64 + kk * 32 + g * 8);
  }

  f32x4 acc[4];
  const f32x4 z = {0.f, 0.f, 0.f, 0.f};
  #pragma unroll
  for (int n = 0; n < 4; ++n) acc[n] = z;
  float m = -1e30f, l = 0.f;

  // staging: per-thread pointers advanced by fixed strides each call.
  // Final over-advance (t = qbH+1, only when its data is unused) reads
  // garbage inside d_ws — never consumed, no fault, deterministic output.
  const int srow = tid >> 3, sc8 = tid & 7;
  const int ssc = sc8 ^ (srow & 7);
  const short* kp = k16 + (int64_t)srow * KVDIM + kvh * 64 + ssc * 8;
  const short* vp = vt16 + (int64_t)(kvh * 64 + srow) * L_SEQ + ssc * 8;
  auto stage1 = [&](int buf, int slot) {
    const int off = (buf * 2 + slot) * 4096;
    gload16(kp, sK + off + tid * 8);
    gload16(vp, sV + off + tid * 8);
    kp += 64 * KVDIM;                      // next kv-tile rows
    vp += 64;                              // next kv-tile cols
  };

  stage1(0, 0);
  stage1(0, 1);                            // qbH >= 16, always valid
  for (int tp = 0; 2 * tp <= qbH; ++tp) {
    const int buf = tp & 1;
    __syncthreads();                       // cur pair landed; other buf free
    if (2 * tp + 2 <= qbH) {
      stage1(buf ^ 1, 0);
      stage1(buf ^ 1, 1);
    }
    const int t0 = 2 * tp, t1 = t0 + 1;
    const bool a0 = (t0 <= myqb);          // wave-uniform
    const bool a1 = (t1 <= myqb);
    if (!a0) continue;                     // barrier count unaffected (top of loop)
    const short* cK0 = sK + (buf * 2 + 0) * 4096;
    const short* cV0 = sV + (buf * 2 + 0) * 4096;
    const short* cK1 = sK + (buf * 2 + 1) * 4096;
    const short* cV1 = sV + (buf * 2 + 1) * 4096;

    // S^T = K * Q for both slots (C cols = q = li, rows = kv)
    f32x4 s0[4], s1[4];
    {
      s16x8 kf[2][4];
      #pragma unroll
      for (int kk = 0; kk < 2; ++kk)
        #pragma unroll
        for (int n = 0; n < 4; ++n)
          kf[kk][n] = *(const s16x8*)(cK0 + (n * 16 + li) * 64 + ((((kk << 2) | g) ^ (li & 7)) << 3));
      #pragma unroll
      for (int n = 0; n < 4; ++n) s0[n] = z;
      __builtin_amdgcn_s_setprio(1);
      #pragma unroll
      for (int kk = 0; kk < 2; ++kk)
        #pragma unroll
        for (int n = 0; n < 4; ++n)
          s0[n] = __builtin_amdgcn_mfma_f32_16x16x32_bf16(kf[kk][n], qf[kk], s0[n], 0, 0, 0);
      __builtin_amdgcn_s_setprio(0);
    }
    if (a1) {
      s16x8 kf[2][4];
      #pragma unroll
      for (int kk = 0; kk < 2; ++kk)
        #pragma unroll
        for (int n = 0; n < 4; ++n)
          kf[kk][n] = *(const s16x8*)(cK1 + (n * 16 + li) * 64 + ((((kk << 2) | g) ^ (li & 7)) << 3));
      #pragma unroll
      for (int n = 0; n < 4; ++n) s1[n] = z;
      __builtin_amdgcn_s_setprio(1);
      #pragma unroll
      for (int kk = 0; kk < 2; ++kk)
        #pragma unroll
        for (int n = 0; n < 4; ++n)
          s1[n] = __builtin_amdgcn_mfma_f32_16x16x32_bf16(kf[kk][n], qf[kk], s1[n], 0, 0, 0);
      __builtin_amdgcn_s_setprio(0);
    }

    // causal mask on diagonal tile
    if (t0 == myqb) {
      const int ql = wl * 16 + li;
      #pragma unroll
      for (int n = 0; n < 4; ++n)
        #pragma unroll
        for (int r = 0; r < 4; ++r)
          if (n * 16 + g * 4 + r > ql) s0[n][r] = -1e30f;
    }
    if (a1 && t1 == myqb) {
      const int ql = wl * 16 + li;
      #pragma unroll
      for (int n = 0; n < 4; ++n)
        #pragma unroll
        for (int r = 0; r < 4; ++r)
          if (n * 16 + g * 4 + r > ql) s1[n][r] = -1e30f;
    }

    // combined online softmax (exp2 domain; Q pre-scaled), one reduce/rescale
    float mx = fmaxf(fmaxf(s0[0][0], s0[0][1]), fmaxf(s0[0][2], s0[0][3]));
    #pragma unroll
    for (int n = 1; n < 4; ++n)
      mx = fmaxf(mx, fmaxf(fmaxf(s0[n][0], s0[n][1]), fmaxf(s0[n][2], s0[n][3])));
    if (a1)
      #pragma unroll
      for (int n = 0; n < 4; ++n)
        mx = fmaxf(mx, fmaxf(fmaxf(s1[n][0], s1[n][1]), fmaxf(s1[n][2], s1[n][3])));
    mx = fmaxf(mx, __shfl_xor(mx, 16, 64));
    mx = fmaxf(mx, __shfl_xor(mx, 32, 64));
    if (__any(mx > m + 8.0f)) {
      const float mn = fmaxf(m, mx);
      const float al = __builtin_amdgcn_exp2f(m - mn);
      m = mn;
      l *= al;
      #pragma unroll
      for (int dt = 0; dt < 4; ++dt)
        #pragma unroll
        for (int r = 0; r < 4; ++r) acc[dt][r] *= al;
    }

    float ps = 0.f;
    // slot0: P -> sPw -> PV
    #pragma unroll
    for (int n = 0; n < 4; ++n) {
      s16x4 pk;
      #pragma unroll
      for (int r = 0; r < 4; ++r) {
        const float p = __builtin_amdgcn_exp2f(s0[n][r] - m);
        pk[r] = f2bf(p);
        ps += p;
      }
      *(s16x4*)(sPw + li * 64 + (((n * 2 + (g >> 1)) ^ (li & 7)) << 3) + (g & 1) * 4) = pk;
    }
    #pragma unroll
    for (int kk = 0; kk < 2; ++kk) {
      s16x8 vf[4];
      #pragma unroll
      for (int dt = 0; dt < 4; ++dt)
        vf[dt] = *(const s16x8*)(cV0 + (dt * 16 + li) * 64 + ((((kk << 2) | g) ^ (li & 7)) << 3));
      s16x8 pf = *(const s16x8*)(sPw + li * 64 + (((kk * 4 + g) ^ (li & 7)) << 3));
      __builtin_amdgcn_s_setprio(1);
      #pragma unroll
      for (int dt = 0; dt < 4; ++dt)
        acc[dt] = __builtin_amdgcn_mfma_f32_16x16x32_bf16(vf[dt], pf, acc[dt], 0, 0, 0);
      __builtin_amdgcn_s_setprio(0);
    }
    // slot1
    if (a1) {
      #pragma unroll
      for (int n = 0; n < 4; ++n) {
        s16x4 pk;
        #pragma unroll
        for (int r = 0; r < 4; ++r) {
          const float p = __builtin_amdgcn_exp2f(s1[n][r] - m);
          pk[r] = f2bf(p);
          ps += p;
        }
        *(s16x4*)(sPw + li * 64 + (((n * 2 + (g >> 1)) ^ (li & 7)) << 3) + (g & 1) * 4) = pk;
      }
      #pragma unroll
      for (int kk = 0; kk < 2; ++kk) {
        s16x8 vf[4];
        #pragma unroll
        for (int dt = 0; dt < 4; ++dt)
          vf[dt] = *(const s16x8*)(cV1 + (dt * 16 + li) * 64 + ((((kk << 2) | g) ^ (li & 7)) << 3));
        s16x8 pf = *(const s16x8*)(sPw + li * 64 + (((kk * 4 + g) ^ (li & 7)) << 3));
        __builtin_amdgcn_s_setprio(1);
        #pragma unroll
        for (int dt = 0; dt < 4; ++dt)
          acc[dt] = __builtin_amdgcn_mfma_f32_16x16x32_bf16(vf[dt], pf, acc[dt], 0, 0, 0);
        __builtin_amdgcn_s_setprio(0);
      }
    }
    // single ps reduce for the pair
    ps += __shfl_xor(ps, 16, 64);
    ps += __shfl_xor(ps, 32, 64);
    l += ps;
  }

  // normalize, per-wave transpose via sPw, coalesced 16B stores
  const float rl = 1.0f / l;
  #pragma unroll
  for (int n2 = 0; n2 < 4; ++n2) {
    s16x4 o;
    #pragma unroll
    for (int r = 0; r < 4; ++r) o[r] = f2bf(acc[n2][r] * rl);
    *(s16x4*)(sPw + li * 64 + (((n2 * 2 + (g >> 1)) ^ (li & 7)) << 3) + (g & 1) * 4) = o;
  }
  #pragma unroll
  for (int half = 0; half < 2; ++half) {
    const int chunk = half * 64 + lane;
    const int q = chunk >> 3, c = chunk & 7;
    s16x8 v = *(const s16x8*)(sPw + q * 64 + ((c ^ (q & 7)) << 3));
    *(s16x8*)(out16 + (int64_t)(myqb * 64 + wl * 16 + q) * HID + h * 64 + c * 8) = v;
  }
}

// ---------------- O projection + residual ----------------
__global__ __launch_bounds__(256) void oproj_kernel(
    const short* __restrict__ ao, const short* __restrict__ wo,
    const float* __restrict__ resid, float* __restrict__ out) {
  __shared__ short sA[2 * 128 * 64];
  __shared__ short sB[2 * 64 * 64];
  const int cb = blockIdx.x, rb = blockIdx.y;
  f32x4 acc[4][2];
  const f32x4 z = {0.f, 0.f, 0.f, 0.f};
  #pragma unroll
  for (int m = 0; m < 4; ++m)
    #pragma unroll
    for (int n = 0; n < 2; ++n) acc[m][n] = z;

  gemm_core_128x64(ao + (int64_t)rb * 128 * HID, wo + (int64_t)cb * 64 * HID, sA, sB, acc);

  const int lane = threadIdx.x & 63;
  const int w = threadIdx.x >> 6, wr = w >> 1, wc = w & 1;
  const int g = lane >> 4, li = lane & 15;
  #pragma unroll
  for (int m = 0; m < 4; ++m) {
    #pragma unroll
    for (int n = 0; n < 2; ++n) {
      const int col = cb * 64 + wc * 32 + n * 16 + li;
      #pragma unroll
      for (int r = 0; r < 4; ++r) {
        const int row = rb * 128 + wr * 64 + m * 16 + g * 4 + r;
        out[(int64_t)row * HID + col] = acc[m][n][r] + resid[(int64_t)row * HID + col];
      }
    }
  }
}

extern "C" void kernel_launch(void* const* d_in, const int* in_sizes, int n_in,
                              void* d_out, int out_size, void* d_ws, size_t ws_size,
                              hipStream_t stream) {
  (void)in_sizes; (void)n_in; (void)out_size; (void)ws_size;
  const float* x      = (const float*)d_in[0];
  const float* norm_w = (const float*)d_in[2];
  const float* Wq     = (const float*)d_in[3];
  const float* Wk     = (const float*)d_in[4];
  const float* Wv     = (const float*)d_in[5];
  const float* Wo     = (const float*)d_in[6];
  const float* rc     = (const float*)d_in[7];
  const float* rs     = (const float*)d_in[8];
  float* out = (float*)d_out;

  char* ws = (char*)d_ws;
  short* wq16 = (short*)(ws);
  short* wk16 = (short*)(ws + 8388608);
  short* wv16 = (short*)(ws + 10485760);
  short* wo16 = (short*)(ws + 12582912);
  short* h16  = (short*)(ws + 20971520);
  short* q16  = (short*)(ws + 29360128);
  short* k16  = (short*)(ws + 37748736);
  short* vt16 = (short*)(ws + 39845888);
  short* ao16 = (short*)(ws + 41943040);

  pre_kernel<<<12288, 256, 0, stream>>>(x, norm_w, Wq, Wk, Wv, Wo,
                                        h16, wq16, wk16, wv16, wo16);
  qkv_kernel<<<dim3(48, 16), 256, 0, stream>>>(h16, wq16, wk16, wv16, q16, k16, vt16, rc, rs);
  attn_kernel<<<dim3(16, NHEAD), 512, 0, stream>>>(q16, k16, vt16, ao16);
  oproj_kernel<<<dim3(32, 16), 256, 0, stream>>>(ao16, wo16, x, out);
}